// Round 13
// baseline (636.177 us; speedup 1.0000x reference)
//
#include <hip/hip_runtime.h>

// Correctly-rounded float decay constants
#define DEC1 0.36787944117144233f   // exp(-1)    : psp1 decay, layer1 refractory
#define DEC2 0.60653065971263342f   // exp(-1/2)  : psp2 decay, layer2 refractory
#define DEC3 0.77880078307140487f   // exp(-1/4)  : psp3 decay, layer3 refractory

typedef float v2f __attribute__((ext_vector_type(2)));

// ---------------------------------------------------------------------------
// Weight re-layout into d_ws:  w1r[c][ky][kx][o] (400 f)  w2r[c][ky][kx][o]
// (576 f)  wupr[o][di][dj][c] pre-flipped for conv_transpose (64 f).
// ---------------------------------------------------------------------------
__global__ void prep_weights(const float* __restrict__ w1,
                             const float* __restrict__ w2,
                             const float* __restrict__ wup,
                             float* __restrict__ wr)
{
    int i = blockIdx.x * 256 + threadIdx.x;
    if (i < 400) {
        int o = i & 7, tap = i >> 3;
        int c = tap / 25, rem = tap % 25, ky = rem / 5, kx = rem % 5;
        wr[i] = w1[((o * 2 + c) * 5 + ky) * 5 + kx];
    }
    if (i < 576) {
        int o = i & 7, tap = i >> 3;
        int c = tap / 9, rem = tap % 9, ky = rem / 3, kx = rem % 3;
        wr[400 + i] = w2[((o * 8 + c) * 3 + ky) * 3 + kx];
    }
    if (i < 64) {
        int c = i & 7, r = i >> 3;
        int dj = r & 1, di = (r >> 1) & 1, o = r >> 2;
        wr[976 + i] = wup[((o * 8 + c) * 2 + (1 - di)) * 2 + (1 - dj)];
    }
}

// spike + following psp, 4 consecutive timesteps (u = float4 over t)
static __device__ __forceinline__ float4 spike_psp4(float4 u, float th, float dref,
                                                    float dq, float& r, float& q)
{
    float4 qv; float v, s;
    v = __fadd_rn(u.x, r); s = (v >= th) ? 1.f : 0.f;
    r = __fsub_rn(__fmul_rn(dref, r), __fmul_rn(th, s));
    q = __fadd_rn(__fmul_rn(dq, q), s); qv.x = q;
    v = __fadd_rn(u.y, r); s = (v >= th) ? 1.f : 0.f;
    r = __fsub_rn(__fmul_rn(dref, r), __fmul_rn(th, s));
    q = __fadd_rn(__fmul_rn(dq, q), s); qv.y = q;
    v = __fadd_rn(u.z, r); s = (v >= th) ? 1.f : 0.f;
    r = __fsub_rn(__fmul_rn(dref, r), __fmul_rn(th, s));
    q = __fadd_rn(__fmul_rn(dq, q), s); qv.z = q;
    v = __fadd_rn(u.w, r); s = (v >= th) ? 1.f : 0.f;
    r = __fsub_rn(__fmul_rn(dref, r), __fmul_rn(th, s));
    q = __fadd_rn(__fmul_rn(dq, q), s); qv.w = q;
    return qv;
}

// final spike (emits hard spikes), 4 timesteps
static __device__ __forceinline__ float4 spike4(float4 u, float th, float dref, float& r)
{
    float4 ov; float v, s;
    v = __fadd_rn(u.x, r); s = (v >= th) ? 1.f : 0.f;
    r = __fsub_rn(__fmul_rn(dref, r), __fmul_rn(th, s)); ov.x = s;
    v = __fadd_rn(u.y, r); s = (v >= th) ? 1.f : 0.f;
    r = __fsub_rn(__fmul_rn(dref, r), __fmul_rn(th, s)); ov.y = s;
    v = __fadd_rn(u.z, r); s = (v >= th) ? 1.f : 0.f;
    r = __fsub_rn(__fmul_rn(dref, r), __fmul_rn(th, s)); ov.z = s;
    v = __fadd_rn(u.w, r); s = (v >= th) ? 1.f : 0.f;
    r = __fsub_rn(__fmul_rn(dref, r), __fmul_rn(th, s)); ov.w = s;
    return ov;
}

// packed fma (v_pk_fma_f32): identical per-element IEEE fma, identical order
#define PKFMA(ALO_, AHI_, WV_, DLO_, DHI_) { \
    v2f wv2_ = { (WV_), (WV_) }; \
    ALO_ = __builtin_elementwise_fma(wv2_, DLO_, ALO_); \
    AHI_ = __builtin_elementwise_fma(wv2_, DHI_, AHI_); }

// psp1 leaky-integrate 4 steps
#define PSP4(V_, X_, st) { \
    V_.x = __fadd_rn(__fmul_rn(DEC1, st),   X_.x); \
    V_.y = __fadd_rn(__fmul_rn(DEC1, V_.x), X_.y); \
    V_.z = __fadd_rn(__fmul_rn(DEC1, V_.y), X_.z); \
    V_.w = __fadd_rn(__fmul_rn(DEC1, V_.z), X_.w); st = V_.w; }

// ---------------------------------------------------------------------------
// R12: wave-specialized producer/consumer pipeline.
//   P = waves 0,1 (tid<128): A (psp1, 1-2 units/lane) + B (conv1 all 8 och,
//       both t-halves, IN-REGISTER spike1/psp2 recurrence -> sP2).
//   Q = waves 2,3: per-wave-private px range (32 px): C-conv (all 8 och per
//       lane, half the LDS reads of R11) -> sP3 accs; C-rec + D same wave
//       (same-wave LDS ordering, no barrier); processes chunk ck-1.
// 2 barriers/chunk (was 5): X between intervals, Y at chunk end.
//   int.1: P:A[ck]        | Q:C-conv[ck-1]   (only sP2 reader)
//   int.2: P:B[ck]->sP2   | Q:C-rec+D[ck-1]  (sP2's only writer)
// sP1 parity dbuf (A[ck] vs D[ck-1] opposite parity); sP2/sP3 single.
// Loop runs 26 iters: P guarded ck<25, Q guarded ck>=1 (natural epilogue).
// Per-accumulator arithmetic order identical to R11 -> bit-identical output.
// LDS 70656 B -> 2 blocks/CU.
// ---------------------------------------------------------------------------
__global__ __launch_bounds__(256, 2)
void snn_fused(const float* __restrict__ spk,
               const float* __restrict__ wr,
               float* __restrict__ out)
{
    const int tid  = threadIdx.x;
    const int b    = blockIdx.x >> 6;
    const int tile = blockIdx.x & 63;
    const int gy0  = (tile >> 3) << 3;
    const int gx0  = (tile & 7) << 3;

    __shared__ float4 sP1[2][2][2][224]; // [parity][ch][thalf][14 rows x 16]
    __shared__ float4 sP2[8][2][100];    // [ch][thalf][10x10 px]  psp2
    __shared__ float4 sP3[8][2][64];     // [ch][thalf][8x8 px]    accs->psp3

    const bool isP = tid < 128;

    // ---------------- P: stage A (units tid and tid+128 if <196) ----------
    const bool u1ok = isP && ((tid + 128) < 196);
    int aidx0 = 0, aoff00 = 0, aoff01 = 0; bool av0 = false;
    int aidx1 = 0, aoff10 = 0, aoff11 = 0; bool av1 = false;
    if (isP) {
        int ry = tid / 14, rx = tid % 14;
        aidx0 = ry * 16 + rx;
        int iy = gy0 - 3 + ry, ix = gx0 - 3 + rx;
        av0 = iy >= 0 && iy < 64 && ix >= 0 && ix < 64;
        if (av0) { aoff00 = (((b*2+0)*64 + iy)*64 + ix)*200;
                   aoff01 = (((b*2+1)*64 + iy)*64 + ix)*200; }
        if (u1ok) {
            int u = tid + 128; ry = u / 14; rx = u % 14;
            aidx1 = ry * 16 + rx;
            iy = gy0 - 3 + ry; ix = gx0 - 3 + rx;
            av1 = iy >= 0 && iy < 64 && ix >= 0 && ix < 64;
            if (av1) { aoff10 = (((b*2+0)*64 + iy)*64 + ix)*200;
                       aoff11 = (((b*2+1)*64 + iy)*64 + ix)*200; }
        }
    }
    float aP00 = 0.f, aP01 = 0.f, aP10 = 0.f, aP11 = 0.f;  // [unit][ch]

    // ---------------- P: stage B mapping (lanes 0..99) ----------------
    int by = 0, bx = 0, bwr = 0;
    { int bpx = tid;
      if (bpx < 80) { by = bpx >> 3; bx = bpx & 7; }
      else          { int t2 = bpx - 80; by = t2 >> 1; bx = 8 + (t2 & 1); }
      bwr = by * 10 + bx; }
    float rB[8], qB[8];
#pragma unroll
    for (int i = 0; i < 8; ++i) { rB[i] = 0.f; qB[i] = 0.f; }

    // ---------------- Q: px-range-private lane mapping ----------------
    const int qt  = tid & 127;
    const int wq  = qt >> 6;            // Q wave (0/1) -> px range 32wq..+31
    const int l   = qt & 63;
    const int pxq = wq * 32 + (l & 31);
    const int sel = l >> 5;             // hC (C-conv) / quad (C-rec) / od (D)
    const int cy  = pxq >> 3, cx = pxq & 7;
    const int diy = gy0 + cy, dix = gx0 + cx;
    float rC[4], qC[4];
#pragma unroll
    for (int i = 0; i < 4; ++i) { rC[i] = 0.f; qC[i] = 0.f; }
    float r3[2][2] = {{0.f, 0.f}, {0.f, 0.f}};   // [ddi][dj]
    // bilinear weights per ddi / dj (jax.image.resize "linear")
    const float ay0  = (diy == 0)  ? 0.f : 0.25f, by0w = (diy == 0)  ? 1.f : 0.75f;
    const float ay1  = (diy == 63) ? 1.f : 0.75f, by1w = (diy == 63) ? 0.f : 0.25f;
    const float ax0  = (dix == 0)  ? 0.f : 0.25f, bx0w = (dix == 0)  ? 1.f : 0.75f;
    const float ax1  = (dix == 63) ? 1.f : 0.75f, bx1w = (dix == 63) ? 0.f : 0.25f;
    const int   didx0 = (cy + 2) * 16 + (cx + 2);   // ddi=0 row base (+16 for ddi=1)

    // ---- P prefetch: chunk 0 ----
    float4 x00 = make_float4(0.f,0.f,0.f,0.f), x01 = x00, x10 = x00, x11 = x00;
    float4 y00 = x00, y01 = x00, y10 = x00, y11 = x00;
    if (av0) {
        x00 = *(const float4*)(spk + aoff00);
        x01 = *(const float4*)(spk + aoff00 + 4);
        x10 = *(const float4*)(spk + aoff01);
        x11 = *(const float4*)(spk + aoff01 + 4);
    }
    if (av1) {
        y00 = *(const float4*)(spk + aoff10);
        y01 = *(const float4*)(spk + aoff10 + 4);
        y10 = *(const float4*)(spk + aoff11);
        y11 = *(const float4*)(spk + aoff11 + 4);
    }

#pragma unroll 1
    for (int ck = 0; ck < 26; ++ck) {
        const int p = ck & 1;

        // ========================= interval 1 ==========================
        if (isP) {
            if (ck < 25) {
                const int t0 = ck * 8;
                float4 v;
                PSP4(v, x00, aP00); sP1[p][0][0][aidx0] = v;
                PSP4(v, x01, aP00); sP1[p][0][1][aidx0] = v;
                PSP4(v, x10, aP01); sP1[p][1][0][aidx0] = v;
                PSP4(v, x11, aP01); sP1[p][1][1][aidx0] = v;
                if (u1ok) {
                    PSP4(v, y00, aP10); sP1[p][0][0][aidx1] = v;
                    PSP4(v, y01, aP10); sP1[p][0][1][aidx1] = v;
                    PSP4(v, y10, aP11); sP1[p][1][0][aidx1] = v;
                    PSP4(v, y11, aP11); sP1[p][1][1][aidx1] = v;
                }
                if (ck < 24) {
                    if (av0) {
                        x00 = *(const float4*)(spk + aoff00 + t0 + 8);
                        x01 = *(const float4*)(spk + aoff00 + t0 + 12);
                        x10 = *(const float4*)(spk + aoff01 + t0 + 8);
                        x11 = *(const float4*)(spk + aoff01 + t0 + 12);
                    }
                    if (av1) {
                        y00 = *(const float4*)(spk + aoff10 + t0 + 8);
                        y01 = *(const float4*)(spk + aoff10 + t0 + 12);
                        y10 = *(const float4*)(spk + aoff11 + t0 + 8);
                        y11 = *(const float4*)(spk + aoff11 + t0 + 12);
                    }
                }
            }
        } else if (ck >= 1) {
            // -------- C-conv[ck-1]: lane (h=sel, pxq), all 8 och --------
            v2f alo[8], ahi[8];
#pragma unroll
            for (int o = 0; o < 8; ++o) { alo[o] = (v2f)(0.f); ahi[o] = (v2f)(0.f); }
#pragma unroll 1
            for (int c = 0; c < 8; ++c) {
#pragma unroll 1
                for (int ky = 0; ky < 3; ++ky) {
                    const float4* r0 = &sP2[c][sel][(cy + ky) * 10 + cx];
                    const float*  wrow = wr + 400 + (c * 9 + ky * 3) * 8;
#pragma unroll
                    for (int kx = 0; kx < 3; ++kx) {
                        float4 d = r0[kx];
                        v2f dlo = { d.x, d.y }, dhi = { d.z, d.w };
#pragma unroll
                        for (int o = 0; o < 8; ++o) {
                            float wv = wrow[kx * 8 + o];
                            PKFMA(alo[o], ahi[o], wv, dlo, dhi);
                        }
                    }
                }
            }
#pragma unroll
            for (int o = 0; o < 8; ++o)
                sP3[o][sel][pxq] = make_float4(alo[o].x, alo[o].y, ahi[o].x, ahi[o].y);
        }
        __syncthreads();   // X: sP1[p] ready; C-conv accs done; sP2 free for B

        // ========================= interval 2 ==========================
        if (isP) {
            if (ck < 25 && tid < 100) {
                // -------- B[ck]: conv1 all 8 och, both halves, in-reg rec ----
                v2f a0lo[8], a0hi[8], a1lo[8], a1hi[8];
#pragma unroll
                for (int o = 0; o < 8; ++o) {
                    a0lo[o] = (v2f)(0.f); a0hi[o] = (v2f)(0.f);
                    a1lo[o] = (v2f)(0.f); a1hi[o] = (v2f)(0.f);
                }
#pragma unroll 1
                for (int c = 0; c < 2; ++c) {
#pragma unroll 1
                    for (int ky = 0; ky < 5; ++ky) {
                        const float4* r0 = &sP1[p][c][0][(by + ky) * 16 + bx];
                        const float4* r1 = &sP1[p][c][1][(by + ky) * 16 + bx];
                        const float*  wrow = wr + (c * 25 + ky * 5) * 8;
#pragma unroll
                        for (int kx = 0; kx < 5; ++kx) {
                            float4 d0 = r0[kx], d1 = r1[kx];
                            v2f d0lo = { d0.x, d0.y }, d0hi = { d0.z, d0.w };
                            v2f d1lo = { d1.x, d1.y }, d1hi = { d1.z, d1.w };
#pragma unroll
                            for (int o = 0; o < 8; ++o) {
                                float wv = wrow[kx * 8 + o];
                                PKFMA(a0lo[o], a0hi[o], wv, d0lo, d0hi);
                                PKFMA(a1lo[o], a1hi[o], wv, d1lo, d1hi);
                            }
                        }
                    }
                }
#pragma unroll
                for (int o = 0; o < 8; ++o) {
                    float4 u0 = make_float4(a0lo[o].x, a0lo[o].y, a0hi[o].x, a0hi[o].y);
                    float4 q0 = spike_psp4(u0, 30.f, DEC1, DEC2, rB[o], qB[o]);
                    sP2[o][0][bwr] = q0;
                    float4 u1 = make_float4(a1lo[o].x, a1lo[o].y, a1hi[o].x, a1hi[o].y);
                    float4 q1 = spike_psp4(u1, 30.f, DEC1, DEC2, rB[o], qB[o]);
                    sP2[o][1][bwr] = q1;
                }
            }
        } else if (ck >= 1) {
            const int pD  = (ck - 1) & 1;
            const int t0m = (ck - 1) * 8;
            // -------- C-rec[ck-1]: lane (quad=sel, pxq), 4 och --------
#pragma unroll
            for (int j = 0; j < 4; ++j) {
                const int o = sel * 4 + j;
                float4 u0 = sP3[o][0][pxq];
                float4 u1 = sP3[o][1][pxq];
                float4 q0 = spike_psp4(u0, 50.f, DEC2, DEC3, rC[j], qC[j]);
                sP3[o][0][pxq] = q0;
                float4 q1 = spike_psp4(u1, 50.f, DEC2, DEC3, rC[j], qC[j]);
                sP3[o][1][pxq] = q1;
            }
            // -------- D[ck-1]: lane (od=sel, pxq); psp3 same-wave-written ----
            float4 p30[8], p31[8];
#pragma unroll
            for (int c2 = 0; c2 < 8; ++c2) {
                p30[c2] = sP3[c2][0][pxq];
                p31[c2] = sP3[c2][1][pxq];
            }
#pragma unroll
            for (int h = 0; h < 2; ++h) {
#pragma unroll
                for (int ddi = 0; ddi < 2; ++ddi) {
                    const float ayv = ddi ? ay1 : ay0;
                    const float byv = ddi ? by1w : by0w;
                    const int base = didx0 + ddi * 16;
                    float4 Pa = sP1[pD][sel][h][base];
                    float4 Pb = sP1[pD][sel][h][base + 1];
                    float4 Pc = sP1[pD][sel][h][base + 2];
                    float4 Qa = sP1[pD][sel][h][base + 16];
                    float4 Qb = sP1[pD][sel][h][base + 17];
                    float4 Qc = sP1[pD][sel][h][base + 18];
#pragma unroll
                    for (int dj = 0; dj < 2; ++dj) {
                        const float axv = dj ? ax1 : ax0;
                        const float bxv = dj ? bx1w : bx0w;
                        v2f tlo = (v2f)(0.f), thi = (v2f)(0.f);
                        const float* wD = wr + 976 + ((sel * 2 + ddi) * 2 + dj) * 8;
#pragma unroll
                        for (int c2 = 0; c2 < 8; ++c2) {
                            float wv = wD[c2];
                            float4 pc = h ? p31[c2] : p30[c2];
                            v2f dlo = { pc.x, pc.y }, dhi = { pc.z, pc.w };
                            PKFMA(tlo, thi, wv, dlo, dhi);
                        }
                        float4 tv = make_float4(tlo.x, tlo.y, thi.x, thi.y);
                        float4 A  = dj ? Pb : Pa;
                        float4 Bv = dj ? Pc : Pb;
                        float4 Cv = dj ? Qb : Qa;
                        float4 Dv = dj ? Qc : Qb;
                        float4 up, u; float ra, rb;
                        ra = __fadd_rn(__fmul_rn(ayv, A.x),  __fmul_rn(byv, Cv.x));
                        rb = __fadd_rn(__fmul_rn(ayv, Bv.x), __fmul_rn(byv, Dv.x));
                        up.x = __fadd_rn(__fmul_rn(axv, ra), __fmul_rn(bxv, rb));
                        ra = __fadd_rn(__fmul_rn(ayv, A.y),  __fmul_rn(byv, Cv.y));
                        rb = __fadd_rn(__fmul_rn(ayv, Bv.y), __fmul_rn(byv, Dv.y));
                        up.y = __fadd_rn(__fmul_rn(axv, ra), __fmul_rn(bxv, rb));
                        ra = __fadd_rn(__fmul_rn(ayv, A.z),  __fmul_rn(byv, Cv.z));
                        rb = __fadd_rn(__fmul_rn(ayv, Bv.z), __fmul_rn(byv, Dv.z));
                        up.z = __fadd_rn(__fmul_rn(axv, ra), __fmul_rn(bxv, rb));
                        ra = __fadd_rn(__fmul_rn(ayv, A.w),  __fmul_rn(byv, Cv.w));
                        rb = __fadd_rn(__fmul_rn(ayv, Bv.w), __fmul_rn(byv, Dv.w));
                        up.w = __fadd_rn(__fmul_rn(axv, ra), __fmul_rn(bxv, rb));
                        u.x = __fadd_rn(tv.x, up.x);
                        u.y = __fadd_rn(tv.y, up.y);
                        u.z = __fadd_rn(tv.z, up.z);
                        u.w = __fadd_rn(tv.w, up.w);
                        float4 ov = spike4(u, 100.f, DEC3, r3[ddi][dj]);
                        float* op = out + ((((b * 2 + sel) * 128 + (2 * diy + ddi)) * 128)
                                           + (2 * dix + dj)) * 200 + t0m + h * 4;
                        *(float4*)op = ov;
                    }
                }
            }
        }
        __syncthreads();   // Y: B's sP2 writes done; D done with sP1[pD]/sP3
    }
}

extern "C" void kernel_launch(void* const* d_in, const int* in_sizes, int n_in,
                              void* d_out, int out_size, void* d_ws, size_t ws_size,
                              hipStream_t stream)
{
    const float* spk = (const float*)d_in[0];
    const float* w1  = (const float*)d_in[1];
    const float* w2  = (const float*)d_in[2];
    const float* wup = (const float*)d_in[3];
    float* outp = (float*)d_out;
    float* wr   = (float*)d_ws;   // 1040 floats of re-laid-out weights

    prep_weights<<<dim3(3), dim3(256), 0, stream>>>(w1, w2, wup, wr);
    snn_fused<<<dim3(512), dim3(256), 0, stream>>>(spk, wr, outp);
}

// Round 14
// 569.594 us; speedup vs baseline: 1.1169x; 1.1169x over previous
//
#include <hip/hip_runtime.h>

// Correctly-rounded float decay constants
#define DEC1 0.36787944117144233f   // exp(-1)    : psp1 decay, layer1 refractory
#define DEC2 0.60653065971263342f   // exp(-1/2)  : psp2 decay, layer2 refractory
#define DEC3 0.77880078307140487f   // exp(-1/4)  : psp3 decay, layer3 refractory

typedef float v2f __attribute__((ext_vector_type(2)));

// ---------------------------------------------------------------------------
// Weight re-layout into d_ws:  w1r[c][ky][kx][o] (400 f)  w2r[c][ky][kx][o]
// (576 f)  wupr[o][di][dj][c] pre-flipped for conv_transpose (64 f).
// ---------------------------------------------------------------------------
__global__ void prep_weights(const float* __restrict__ w1,
                             const float* __restrict__ w2,
                             const float* __restrict__ wup,
                             float* __restrict__ wr)
{
    int i = blockIdx.x * 256 + threadIdx.x;
    if (i < 400) {
        int o = i & 7, tap = i >> 3;
        int c = tap / 25, rem = tap % 25, ky = rem / 5, kx = rem % 5;
        wr[i] = w1[((o * 2 + c) * 5 + ky) * 5 + kx];
    }
    if (i < 576) {
        int o = i & 7, tap = i >> 3;
        int c = tap / 9, rem = tap % 9, ky = rem / 3, kx = rem % 3;
        wr[400 + i] = w2[((o * 8 + c) * 3 + ky) * 3 + kx];
    }
    if (i < 64) {
        int c = i & 7, r = i >> 3;
        int dj = r & 1, di = (r >> 1) & 1, o = r >> 2;
        wr[976 + i] = wup[((o * 8 + c) * 2 + (1 - di)) * 2 + (1 - dj)];
    }
}

// spike + following psp, 4 consecutive timesteps (u = float4 over t)
static __device__ __forceinline__ float4 spike_psp4(float4 u, float th, float dref,
                                                    float dq, float& r, float& q)
{
    float4 qv; float v, s;
    v = __fadd_rn(u.x, r); s = (v >= th) ? 1.f : 0.f;
    r = __fsub_rn(__fmul_rn(dref, r), __fmul_rn(th, s));
    q = __fadd_rn(__fmul_rn(dq, q), s); qv.x = q;
    v = __fadd_rn(u.y, r); s = (v >= th) ? 1.f : 0.f;
    r = __fsub_rn(__fmul_rn(dref, r), __fmul_rn(th, s));
    q = __fadd_rn(__fmul_rn(dq, q), s); qv.y = q;
    v = __fadd_rn(u.z, r); s = (v >= th) ? 1.f : 0.f;
    r = __fsub_rn(__fmul_rn(dref, r), __fmul_rn(th, s));
    q = __fadd_rn(__fmul_rn(dq, q), s); qv.z = q;
    v = __fadd_rn(u.w, r); s = (v >= th) ? 1.f : 0.f;
    r = __fsub_rn(__fmul_rn(dref, r), __fmul_rn(th, s));
    q = __fadd_rn(__fmul_rn(dq, q), s); qv.w = q;
    return qv;
}

// final spike (emits hard spikes), 4 timesteps
static __device__ __forceinline__ float4 spike4(float4 u, float th, float dref, float& r)
{
    float4 ov; float v, s;
    v = __fadd_rn(u.x, r); s = (v >= th) ? 1.f : 0.f;
    r = __fsub_rn(__fmul_rn(dref, r), __fmul_rn(th, s)); ov.x = s;
    v = __fadd_rn(u.y, r); s = (v >= th) ? 1.f : 0.f;
    r = __fsub_rn(__fmul_rn(dref, r), __fmul_rn(th, s)); ov.y = s;
    v = __fadd_rn(u.z, r); s = (v >= th) ? 1.f : 0.f;
    r = __fsub_rn(__fmul_rn(dref, r), __fmul_rn(th, s)); ov.z = s;
    v = __fadd_rn(u.w, r); s = (v >= th) ? 1.f : 0.f;
    r = __fsub_rn(__fmul_rn(dref, r), __fmul_rn(th, s)); ov.w = s;
    return ov;
}

// packed fma: two independent t-elements per v_pk_fma_f32. Same IEEE fma
// rounding per element, same accumulation order -> bit-identical output.
#define PKFMA(ALO_, AHI_, WV_, DLO_, DHI_) { \
    v2f wv2_ = { (WV_), (WV_) }; \
    ALO_ = __builtin_elementwise_fma(wv2_, DLO_, ALO_); \
    AHI_ = __builtin_elementwise_fma(wv2_, DHI_, AHI_); }

// psp1 leaky-integrate 4 steps: state in `st`, input X_, write V_ out
#define PSP4(V_, X_, st) { \
    V_.x = __fadd_rn(__fmul_rn(DEC1, st),   X_.x); \
    V_.y = __fadd_rn(__fmul_rn(DEC1, V_.x), X_.y); \
    V_.z = __fadd_rn(__fmul_rn(DEC1, V_.y), X_.z); \
    V_.w = __fadd_rn(__fmul_rn(DEC1, V_.z), X_.w); st = V_.w; }

// ---------------------------------------------------------------------------
// R13 = exact revert to R11 (best: 395 us steady-state). Final kernel.
// Design: R7 skeleton (conv/rec split, 5 barriers/chunk, chunk=8, sP1 parity
// dbuf, register prefetch) + v_pk_fma_f32 packed conv FMAs (R11).
// Tested-and-rejected departures (keep for the record):
//  - R3  finer tile / 4 blocks/CU: 3x LDS read amplification, regressed.
//  - R8  paired 64B stores: broke L2 dirty-line merging (+300 MB), regressed.
//  - R10 sP1 stride 17: conflicts are structural wave64-b128 cost, neutral.
//  - R12 wave-specialized P/Q (2 barriers): block phase drift halved L2 line
//    survival (FETCH 135->270 MB), regressed. The 5-barrier lockstep is what
//    keeps input/output 128B-line reuse alive (lines span 4 t-chunks).
// Steady state: VALU ~47%, LDS pipe ~55-60%, HBM 13%, 2 blocks/CU (grid-
// capped at 512 blocks). Remaining slack is barrier-coupled latency that
// every tested restructure converts into worse memory traffic.
// ---------------------------------------------------------------------------
__global__ __launch_bounds__(256, 2)
void snn_fused(const float* __restrict__ spk,
               const float* __restrict__ wr,
               float* __restrict__ out)
{
    const int tid  = threadIdx.x;
    const int b    = blockIdx.x >> 6;
    const int tile = blockIdx.x & 63;
    const int gy0  = (tile >> 3) << 3;
    const int gx0  = (tile & 7) << 3;

    __shared__ float4 sP1[2][2][2][224]; // [parity][ch][thalf][14 rows x 16]
    __shared__ float4 sP2[8][2][100];    // [ch][thalf][10x10 px] (acc then psp2)
    __shared__ float4 sP3[8][2][64];     // [ch][thalf][ 8x8 px]  (acc then psp3)

    // persistent per-thread recurrent state
    float aP0 = 0.f, aP1 = 0.f;
    float rB[4], qB[4];
    float rC[2] = {0.f, 0.f}, qC[2] = {0.f, 0.f};
    float r3[2] = {0.f, 0.f};
#pragma unroll
    for (int i = 0; i < 4; ++i) { rB[i] = 0.f; qB[i] = 0.f; }

    // ---- stage A: psp1 region 14x14, threads 0..195 ----
    const int ary = tid / 14, arx = tid % 14;
    const int aidx = ary * 16 + arx;           // padded row stride 16
    const int aiy = gy0 - 3 + ary, aix = gx0 - 3 + arx;
    const bool avalid = (tid < 196) && (aiy >= 0) && (aiy < 64) && (aix >= 0) && (aix < 64);
    const int aoff0 = avalid ? (((b * 2 + 0) * 64 + aiy) * 64 + aix) * 200 : 0;
    const int aoff1 = avalid ? (((b * 2 + 1) * 64 + aiy) * 64 + aix) * 200 : 0;

    // ---- stage B: thread = (bh = tid>>7, bpx = tid&127 < 100) ----
    const int bh   = __builtin_amdgcn_readfirstlane(tid >> 7);
    const int bpx  = tid & 127;
    int by_, bx_;
    if (bpx < 80) { by_ = bpx >> 3; bx_ = bpx & 7; }
    else          { int t2 = bpx - 80; by_ = t2 >> 1; bx_ = 8 + (t2 & 1); }
    const int by = by_, bx = bx_;
    const int bwr = by * 10 + bx;              // sP2 px index (bijective)
    const int ochB = tid >> 7;                 // B-rec state owner quad

    // ---- C-conv: thread = (ch2 = tid>>7 -> t-half, cop -> och quad, px) ----
    const int ch2  = __builtin_amdgcn_readfirstlane(tid >> 7);
    const int cop  = __builtin_amdgcn_readfirstlane(tid >> 6) & 1;
    const int cpx  = tid & 63;
    const int cy   = cpx >> 3, cx = cpx & 7;
    const int och2 = (tid >> 6) * 2;           // C-rec state owner pair

    // ---- stage D: thread = (od = t>>7, ddi = (t>>6)&1, px) ----
    const int od  = tid >> 7;
    const int ddi = (tid >> 6) & 1;
    const int dpx = tid & 63;
    const int dy  = dpx >> 3, dxx = dpx & 7;
    const int diy = gy0 + dy, dix = gx0 + dxx;

    // bilinear 2x upsample weights (jax.image.resize "linear")
    const float ay  = ddi ? ((diy == 63) ? 1.f : 0.75f) : ((diy == 0) ? 0.f : 0.25f);
    const float byw = ddi ? ((diy == 63) ? 0.f : 0.25f) : ((diy == 0) ? 1.f : 0.75f);
    const float ax0 = (dix == 0)  ? 0.f : 0.25f;   // dj = 0
    const float bx0 = (dix == 0)  ? 1.f : 0.75f;
    const float ax1 = (dix == 63) ? 1.f : 0.75f;   // dj = 1
    const float bx1 = (dix == 63) ? 0.f : 0.25f;
    const int   didx = (dy + 2 + ddi) * 16 + (dxx + 2);

    // ---- prefetch registers: chunk 0's input ----
    float4 x00 = make_float4(0.f,0.f,0.f,0.f), x01 = x00, x10 = x00, x11 = x00;
    if (avalid) {
        x00 = *(const float4*)(spk + aoff0);
        x01 = *(const float4*)(spk + aoff0 + 4);
        x10 = *(const float4*)(spk + aoff1);
        x11 = *(const float4*)(spk + aoff1 + 4);
    }

#pragma unroll 1
    for (int ck = 0; ck < 25; ++ck) {
        const int t0 = ck * 8;
        const int p  = ck & 1;

        // ================= stage A: psp1 + prefetch next chunk =============
        if (tid < 196) {
            float4 v;
            PSP4(v, x00, aP0); sP1[p][0][0][aidx] = v;
            PSP4(v, x01, aP0); sP1[p][0][1][aidx] = v;
            PSP4(v, x10, aP1); sP1[p][1][0][aidx] = v;
            PSP4(v, x11, aP1); sP1[p][1][1][aidx] = v;
            if (ck < 24 && avalid) {
                x00 = *(const float4*)(spk + aoff0 + t0 + 8);
                x01 = *(const float4*)(spk + aoff0 + t0 + 12);
                x10 = *(const float4*)(spk + aoff1 + t0 + 8);
                x11 = *(const float4*)(spk + aoff1 + t0 + 12);
            }
        }
        __syncthreads();   // b1: sP1[p] ready; prev-chunk C-conv done with sP2

        // ============ stage B-conv: conv1 5x5, all 8 och, one t-half =======
        if (bpx < 100) {
            v2f alo[8], ahi[8];
#pragma unroll
            for (int o = 0; o < 8; ++o) { alo[o] = (v2f)(0.f); ahi[o] = (v2f)(0.f); }
#pragma unroll 1
            for (int c = 0; c < 2; ++c) {
#pragma unroll 1
                for (int ky = 0; ky < 5; ++ky) {
                    const float4* r0 = &sP1[p][c][bh][(by + ky) * 16 + bx];
                    const float*  wrow = wr + (c * 25 + ky * 5) * 8;
#pragma unroll
                    for (int kx = 0; kx < 5; ++kx) {
                        float4 d = r0[kx];
                        v2f dlo = { d.x, d.y }, dhi = { d.z, d.w };
#pragma unroll
                        for (int o = 0; o < 8; ++o) {
                            float wv = wrow[kx * 8 + o];
                            PKFMA(alo[o], ahi[o], wv, dlo, dhi);
                        }
                    }
                }
            }
#pragma unroll
            for (int o = 0; o < 8; ++o)
                sP2[o][bh][bwr] = make_float4(alo[o].x, alo[o].y, ahi[o].x, ahi[o].y);
        }
        __syncthreads();   // b2: acc ready

        // ============ stage B-rec: spike1 + psp2 in-place on sP2 ===========
        if (bpx < 100) {
#pragma unroll
            for (int j = 0; j < 4; ++j) {
                const int o = ochB * 4 + j;
                float4 u0 = sP2[o][0][bwr];
                float4 u1 = sP2[o][1][bwr];
                float4 q0 = spike_psp4(u0, 30.f, DEC1, DEC2, rB[j], qB[j]);
                sP2[o][0][bwr] = q0;
                float4 q1 = spike_psp4(u1, 30.f, DEC1, DEC2, rB[j], qB[j]);
                sP2[o][1][bwr] = q1;
            }
        }
        __syncthreads();   // b3: psp2 ready

        // ============ stage C-conv: conv2 3x3, och quad, one t-half ========
        {
            v2f alo[4], ahi[4];
#pragma unroll
            for (int j = 0; j < 4; ++j) { alo[j] = (v2f)(0.f); ahi[j] = (v2f)(0.f); }
            const float* wC = wr + 400 + cop * 4;
#pragma unroll 1
            for (int c = 0; c < 8; ++c) {
#pragma unroll 1
                for (int ky = 0; ky < 3; ++ky) {
                    const float4* r0 = &sP2[c][ch2][(cy + ky) * 10 + cx];
                    const float*  wrow = wC + (c * 9 + ky * 3) * 8;
#pragma unroll
                    for (int kx = 0; kx < 3; ++kx) {
                        float4 d = r0[kx];
                        v2f dlo = { d.x, d.y }, dhi = { d.z, d.w };
#pragma unroll
                        for (int j = 0; j < 4; ++j) {
                            float wv = wrow[kx * 8 + j];
                            PKFMA(alo[j], ahi[j], wv, dlo, dhi);
                        }
                    }
                }
            }
#pragma unroll
            for (int j = 0; j < 4; ++j)
                sP3[cop * 4 + j][ch2][cpx] =
                    make_float4(alo[j].x, alo[j].y, ahi[j].x, ahi[j].y);
        }
        __syncthreads();   // b4: acc ready

        // ============ stage C-rec: spike2 + psp3 in-place on sP3 ===========
        {
#pragma unroll
            for (int j = 0; j < 2; ++j) {
                const int o = och2 + j;
                float4 u0 = sP3[o][0][cpx];
                float4 u1 = sP3[o][1][cpx];
                float4 q0 = spike_psp4(u0, 50.f, DEC2, DEC3, rC[j], qC[j]);
                sP3[o][0][cpx] = q0;
                float4 q1 = spike_psp4(u1, 50.f, DEC2, DEC3, rC[j], qC[j]);
                sP3[o][1][cpx] = q1;
            }
        }
        __syncthreads();   // b5: psp3 ready

        // ============ stage D: convT 2x2 s2 + psp1 bilinear-up + spike3 ====
        {
#pragma unroll 1
            for (int h = 0; h < 2; ++h) {
                float4 p3[8];
#pragma unroll
                for (int c = 0; c < 8; ++c) p3[c] = sP3[c][h][dpx];
                float4 P0a = sP1[p][od][h][didx];
                float4 P0b = sP1[p][od][h][didx + 1];
                float4 P0c = sP1[p][od][h][didx + 2];
                float4 P1a = sP1[p][od][h][didx + 16];
                float4 P1b = sP1[p][od][h][didx + 17];
                float4 P1c = sP1[p][od][h][didx + 18];
#pragma unroll
                for (int dj = 0; dj < 2; ++dj) {
                    const float ax  = dj ? ax1 : ax0;
                    const float bxw = dj ? bx1 : bx0;
                    v2f tlo = (v2f)(0.f), thi = (v2f)(0.f);
                    const float* wD = wr + 976 + ((od * 2 + ddi) * 2 + dj) * 8;
#pragma unroll
                    for (int c = 0; c < 8; ++c) {
                        float wv = wD[c];
                        v2f dlo = { p3[c].x, p3[c].y }, dhi = { p3[c].z, p3[c].w };
                        PKFMA(tlo, thi, wv, dlo, dhi);
                    }
                    float4 tv = make_float4(tlo.x, tlo.y, thi.x, thi.y);
                    float4 A  = dj ? P0b : P0a;
                    float4 Bv = dj ? P0c : P0b;
                    float4 Cv = dj ? P1b : P1a;
                    float4 Dv = dj ? P1c : P1b;
                    float4 up, u; float ra, rb;
                    ra = __fadd_rn(__fmul_rn(ay, A.x),  __fmul_rn(byw, Cv.x));
                    rb = __fadd_rn(__fmul_rn(ay, Bv.x), __fmul_rn(byw, Dv.x));
                    up.x = __fadd_rn(__fmul_rn(ax, ra), __fmul_rn(bxw, rb));
                    ra = __fadd_rn(__fmul_rn(ay, A.y),  __fmul_rn(byw, Cv.y));
                    rb = __fadd_rn(__fmul_rn(ay, Bv.y), __fmul_rn(byw, Dv.y));
                    up.y = __fadd_rn(__fmul_rn(ax, ra), __fmul_rn(bxw, rb));
                    ra = __fadd_rn(__fmul_rn(ay, A.z),  __fmul_rn(byw, Cv.z));
                    rb = __fadd_rn(__fmul_rn(ay, Bv.z), __fmul_rn(byw, Dv.z));
                    up.z = __fadd_rn(__fmul_rn(ax, ra), __fmul_rn(bxw, rb));
                    ra = __fadd_rn(__fmul_rn(ay, A.w),  __fmul_rn(byw, Cv.w));
                    rb = __fadd_rn(__fmul_rn(ay, Bv.w), __fmul_rn(byw, Dv.w));
                    up.w = __fadd_rn(__fmul_rn(ax, ra), __fmul_rn(bxw, rb));
                    u.x = __fadd_rn(tv.x, up.x);
                    u.y = __fadd_rn(tv.y, up.y);
                    u.z = __fadd_rn(tv.z, up.z);
                    u.w = __fadd_rn(tv.w, up.w);
                    float4 ov = spike4(u, 100.f, DEC3, r3[dj]);
                    float* op = out + ((((b * 2 + od) * 128 + (2 * diy + ddi)) * 128)
                                       + (2 * dix + dj)) * 200 + t0 + h * 4;
                    *(float4*)op = ov;
                }
            }
        }
        // no end barrier: next A writes sP1[p^1]; sP2 safe until next B-conv
        // (separated by b1'); sP3 safe until next C-conv (separated by b3').
    }
}

extern "C" void kernel_launch(void* const* d_in, const int* in_sizes, int n_in,
                              void* d_out, int out_size, void* d_ws, size_t ws_size,
                              hipStream_t stream)
{
    const float* spk = (const float*)d_in[0];
    const float* w1  = (const float*)d_in[1];
    const float* w2  = (const float*)d_in[2];
    const float* wup = (const float*)d_in[3];
    float* outp = (float*)d_out;
    float* wr   = (float*)d_ws;   // 1040 floats of re-laid-out weights

    prep_weights<<<dim3(3), dim3(256), 0, stream>>>(w1, w2, wup, wr);
    snn_fused<<<dim3(512), dim3(256), 0, stream>>>(spk, wr, outp);
}